// Round 8
// baseline (281.561 us; speedup 1.0000x reference)
//
#include <hip/hip_runtime.h>
#include <cstdint>

#define BB 2048
#define TT 200
#define DD 128
#define H1 128
#define H2 64
#define MASK_PAD -4294967295.0f

typedef __attribute__((ext_vector_type(8))) short short8;
typedef __attribute__((ext_vector_type(4))) float floatx4;

#define ATTN_OFF 57344  // float offset of attn[2048][200] in ws

static __device__ __forceinline__ unsigned short f2bf(float x) {
  union { float f; unsigned int u; } v; v.f = x;
  unsigned int r = v.u + 0x7FFF + ((v.u >> 16) & 1);  // RNE
  return (unsigned short)(r >> 16);
}

// ---------------------------------------------------------------------------
// Fold kernel -> ws:
//   Wqac[d][h] = W0a[d][h] + W0c[d][h]          fp32 [128][128] @ float 0
//   WkT [h][d] = (W0b - W0c)[d][h]              fp32 [128][128] @ float 16384
//   WdT [h][d] = W0d[d][h]                      fp32 [128][128] @ float 32768
//   W1tb[g][h] = bf16(W1[h][g])                 bf16 [64][128]  @ float 49152
// ---------------------------------------------------------------------------
__global__ void din_fold(const float* __restrict__ W0,
                         const float* __restrict__ W1,
                         float* __restrict__ ws) {
  int i = blockIdx.x * blockDim.x + threadIdx.x;
  if (i < 16384) {
    int d = i >> 7, h = i & 127;
    ws[i] = W0[d * 128 + h] + W0[(256 + d) * 128 + h];
  } else if (i < 32768) {
    int j = i - 16384; int h = j >> 7, d = j & 127;
    ws[16384 + j] = W0[(128 + d) * 128 + h] - W0[(256 + d) * 128 + h];
  } else if (i < 49152) {
    int j = i - 32768; int h = j >> 7, d = j & 127;
    ws[32768 + j] = W0[(384 + d) * 128 + h];
  } else if (i < 57344) {
    int j = i - 49152; int g = j >> 7, h = j & 127;
    ((unsigned short*)(ws + 49152))[j] = f2bf(W1[h * 64 + g]);
  }
}

// ---------------------------------------------------------------------------
// Kernel A: logits + softmax -> attn. One block per b, 4 independent waves.
// Same structure as R6 (folded Wb in LDS, wave-private tiles, barrier-free
// main loop, next-tile key prefetch) but with JIT a0/a1 loads and per-ks
// A-frag cvt so the working set fits 128 VGPRs with ZERO spill.
// ---------------------------------------------------------------------------
__global__ __launch_bounds__(256, 2) void din_logits(
    const float* __restrict__ query, const float* __restrict__ key,
    const int* __restrict__ mask,
    const float* __restrict__ b0, const float* __restrict__ a0,
    const float* __restrict__ b1, const float* __restrict__ a1,
    const float* __restrict__ Wout, const float* __restrict__ bout,
    const float* __restrict__ ws, float* __restrict__ attn_out) {
  const int b = blockIdx.x;
  const int tid = threadIdx.x;
  const int w = tid >> 6;
  const int l = tid & 63;

  __shared__ unsigned short Wb[128 * 128];    // 32 KB folded W_b bf16 (swz)
  __shared__ unsigned short W1s[64 * 128];    // 16 KB W1^T bf16 (swz)
  __shared__ unsigned short A2[4][16 * 128];  // 16 KB per-wave H0 (swz)
  __shared__ float qs[DD];
  __shared__ float qas[H1];
  __shared__ float logitsAll[208];
  __shared__ float red4[8];

  const float* Wqac = ws;
  const float* WkT  = ws + 16384;
  const float* WdT  = ws + 32768;
  const unsigned short* W1tb = (const unsigned short*)(ws + 49152);

  // ---- stage q ----
  if (tid < DD) qs[tid] = query[(size_t)b * DD + tid];
  __syncthreads();

  // ---- build Wb = bf16(WkT[h][d] + q[d]*WdT[h][d]), swizzled ----
  #pragma unroll
  for (int j = 0; j < 16; ++j) {
    int flat = j * 1024 + tid * 4;
    int h = flat >> 7, d = flat & 127;
    float4 kv = *(const float4*)(WkT + flat);
    float4 dv = *(const float4*)(WdT + flat);
    ushort4 u;
    u.x = f2bf(kv.x + qs[d] * dv.x);
    u.y = f2bf(kv.y + qs[d + 1] * dv.y);
    u.z = f2bf(kv.z + qs[d + 2] * dv.z);
    u.w = f2bf(kv.w + qs[d + 3] * dv.w);
    *(ushort4*)((char*)Wb + h * 256 + ((d * 2) ^ ((h & 7) << 4))) = u;
  }
  // ---- copy W1s (swizzled) ----
  #pragma unroll
  for (int j = 0; j < 8; ++j) {
    int flat = j * 1024 + tid * 4;
    int g = flat >> 7, h = flat & 127;
    ushort4 u = *(const ushort4*)(W1tb + flat);
    *(ushort4*)((char*)W1s + g * 256 + ((h * 2) ^ ((g & 7) << 4))) = u;
  }
  // ---- qA ----
  if (tid < H1) {
    float acc = b0[tid];
    const float* wq = Wqac + tid;
    #pragma unroll 8
    for (int d = 0; d < DD; ++d) acc += qs[d] * wq[d * 128];
    qas[tid] = acc;
  }
  __syncthreads();  // Wb, W1s, qas ready — last barrier before softmax

  const int kgrp = l >> 4;            // 0..3
  const int lr = l & 15;
  char* a2b = (char*)A2[w];

  // per-lane epilogue-2 constants (g-cols this lane owns)
  float b1v[4], wov[4];
  #pragma unroll
  for (int nt = 0; nt < 4; ++nt) {
    int g = nt * 16 + lr;
    b1v[nt] = b1[g]; wov[nt] = Wout[g];
  }
  const float bout0 = bout[0];

  // ---- prologue: prefetch first tile's key chunk ----
  float4 fa[8];
  int mt = w;
  {
    int trow = mt * 16 + lr; if (trow > 199) trow = 199;
    const float* ar = key + ((size_t)b * TT + trow) * DD + kgrp * 8;
    #pragma unroll
    for (int ks = 0; ks < 4; ++ks) {
      fa[2 * ks]     = *(const float4*)(ar + ks * 32);
      fa[2 * ks + 1] = *(const float4*)(ar + ks * 32 + 4);
    }
  }

  // =============== barrier-free per-wave M-tile loop ===============
  #pragma unroll 1
  while (mt < 13) {
    // ---- GEMM1: full width (8 n-tiles), B from LDS; per-ks cvt of A ----
    floatx4 acc1[8];
    #pragma unroll
    for (int nt = 0; nt < 8; ++nt) acc1[nt] = (floatx4)(0.0f);
    #pragma unroll
    for (int ks = 0; ks < 4; ++ks) {
      float4 f0 = fa[2 * ks], f1 = fa[2 * ks + 1];
      short8 af;
      af[0] = (short)f2bf(f0.x); af[1] = (short)f2bf(f0.y);
      af[2] = (short)f2bf(f0.z); af[3] = (short)f2bf(f0.w);
      af[4] = (short)f2bf(f1.x); af[5] = (short)f2bf(f1.y);
      af[6] = (short)f2bf(f1.z); af[7] = (short)f2bf(f1.w);
      #pragma unroll
      for (int nt = 0; nt < 8; ++nt) {
        int h = nt * 16 + lr;
        short8 bf = *(const short8*)((const char*)Wb + h * 256 +
                                     ((ks * 64 + kgrp * 16) ^ ((h & 7) << 4)));
        acc1[nt] = __builtin_amdgcn_mfma_f32_16x16x32_bf16(af, bf, acc1[nt], 0, 0, 0);
      }
    }
    // ---- prefetch NEXT tile's key (hidden under epilogues/GEMM2) ----
    int mtn = mt + 4;
    if (mtn < 13) {
      int trow = mtn * 16 + lr; if (trow > 199) trow = 199;
      const float* ar = key + ((size_t)b * TT + trow) * DD + kgrp * 8;
      #pragma unroll
      for (int ks = 0; ks < 4; ++ks) {
        fa[2 * ks]     = *(const float4*)(ar + ks * 32);
        fa[2 * ks + 1] = *(const float4*)(ar + ks * 32 + 4);
      }
    }
    // ---- epilogue 1: +qA, PReLU(a0 JIT), write H0 to private LDS (swz) ----
    #pragma unroll
    for (int nt = 0; nt < 8; ++nt) {
      int h = nt * 16 + lr;
      float qa = qas[h];
      #pragma unroll
      for (int r = 0; r < 4; ++r) {
        int t_loc = kgrp * 4 + r;
        int tg = mt * 16 + t_loc; if (tg > 199) tg = 199;
        float v = acc1[nt][r] + qa;
        float a = a0[tg * H1 + h];
        v = v > 0.0f ? v : a * v;
        *(unsigned short*)(a2b + t_loc * 256 + ((h * 2) ^ ((t_loc & 7) << 4))) = f2bf(v);
      }
    }
    // ---- GEMM2: A from private LDS, B from LDS W1s ----
    short8 a2f[4];
    #pragma unroll
    for (int ks = 0; ks < 4; ++ks) {
      a2f[ks] = *(const short8*)(a2b + lr * 256 +
                                 ((ks * 64 + kgrp * 16) ^ ((lr & 7) << 4)));
    }
    floatx4 acc2[4];
    #pragma unroll
    for (int nt = 0; nt < 4; ++nt) acc2[nt] = (floatx4)(0.0f);
    #pragma unroll
    for (int ks = 0; ks < 4; ++ks) {
      #pragma unroll
      for (int nt = 0; nt < 4; ++nt) {
        int g = nt * 16 + lr;
        short8 bf = *(const short8*)((const char*)W1s + g * 256 +
                                     ((ks * 64 + kgrp * 16) ^ ((g & 7) << 4)));
        acc2[nt] = __builtin_amdgcn_mfma_f32_16x16x32_bf16(a2f[ks], bf, acc2[nt], 0, 0, 0);
      }
    }
    // ---- epilogue 2: +b1, PReLU(a1 JIT), *Wout, 16-lane reduce -> logits ----
    float p[4] = {0.f, 0.f, 0.f, 0.f};
    #pragma unroll
    for (int nt = 0; nt < 4; ++nt) {
      int g = nt * 16 + lr;
      #pragma unroll
      for (int r = 0; r < 4; ++r) {
        int tg = mt * 16 + kgrp * 4 + r; if (tg > 199) tg = 199;
        float x = acc2[nt][r] + b1v[nt];
        float a = a1[tg * H2 + g];
        x = x > 0.0f ? x : a * x;
        p[r] += x * wov[nt];
      }
    }
    #pragma unroll
    for (int m = 1; m < 16; m <<= 1) {
      #pragma unroll
      for (int r = 0; r < 4; ++r) p[r] += __shfl_xor(p[r], m);
    }
    if (lr == 0) {
      #pragma unroll
      for (int r = 0; r < 4; ++r) {
        int tg = mt * 16 + kgrp * 4 + r;
        if (tg < TT) {
          int mk = mask[(size_t)b * TT + tg];
          logitsAll[tg] = (mk == 0) ? MASK_PAD : (bout0 + p[r]);
        }
      }
    }
    mt = mtn;
  }
  __syncthreads();

  // =================== softmax -> normalized attn ===================
  float lv = (tid < TT) ? logitsAll[tid] : -INFINITY;
  {
    float m = lv;
    #pragma unroll
    for (int off = 32; off >= 1; off >>= 1) m = fmaxf(m, __shfl_xor(m, off));
    if (l == 0) red4[w] = m;
  }
  __syncthreads();
  float mx = fmaxf(fmaxf(red4[0], red4[1]), fmaxf(red4[2], red4[3]));
  float e = (tid < TT) ? __expf(lv - mx) : 0.0f;
  {
    float s = e;
    #pragma unroll
    for (int off = 32; off >= 1; off >>= 1) s += __shfl_xor(s, off);
    if (l == 0) red4[4 + w] = s;
  }
  __syncthreads();
  float denom = red4[4] + red4[5] + red4[6] + red4[7];
  float inv = 1.0f / denom;
  if (tid < TT) attn_out[(size_t)b * TT + tid] = e * inv;
}

// ---------------------------------------------------------------------------
// Kernel B: PV. out[b][d] = sum_t attn[b][t] * val[b][t][d].
// ---------------------------------------------------------------------------
__global__ __launch_bounds__(256) void din_pv(
    const float* __restrict__ val, const float* __restrict__ attn,
    float* __restrict__ out) {
  const int b = blockIdx.x;
  const int tid = threadIdx.x;
  __shared__ float eL[TT];
  __shared__ float red[8 * DD];

  if (tid < TT) eL[tid] = attn[(size_t)b * TT + tid];
  __syncthreads();

  const int group = tid >> 5;
  const int d4 = (tid & 31) * 4;
  const float* vb = val + (size_t)b * TT * DD;
  float4 acc4 = make_float4(0.f, 0.f, 0.f, 0.f);
  #pragma unroll 5
  for (int t = group * 25; t < group * 25 + 25; ++t) {
    float4 v = *(const float4*)(vb + (size_t)t * DD + d4);
    float wt = eL[t];
    acc4.x += wt * v.x; acc4.y += wt * v.y;
    acc4.z += wt * v.z; acc4.w += wt * v.w;
  }
  *(float4*)&red[group * DD + d4] = acc4;
  __syncthreads();
  if (tid < DD) {
    float s = 0.0f;
    #pragma unroll
    for (int g = 0; g < 8; ++g) s += red[g * DD + tid];
    out[(size_t)b * DD + tid] = s;
  }
}

extern "C" void kernel_launch(void* const* d_in, const int* in_sizes, int n_in,
                              void* d_out, int out_size, void* d_ws, size_t ws_size,
                              hipStream_t stream) {
  const float* query = (const float*)d_in[0];
  const float* key   = (const float*)d_in[1];
  const float* val   = (const float*)d_in[2];
  const int*   mask  = (const int*)d_in[3];
  const float* W0    = (const float*)d_in[4];
  const float* b0    = (const float*)d_in[5];
  const float* a0    = (const float*)d_in[6];
  const float* W1    = (const float*)d_in[7];
  const float* b1    = (const float*)d_in[8];
  const float* a1    = (const float*)d_in[9];
  const float* Wout  = (const float*)d_in[10];
  const float* bout  = (const float*)d_in[11];
  float* out = (float*)d_out;
  float* ws  = (float*)d_ws;
  float* attn = ws + ATTN_OFF;

  hipLaunchKernelGGL(din_fold, dim3(224), dim3(256), 0, stream, W0, W1, ws);
  hipLaunchKernelGGL(din_logits, dim3(BB), dim3(256), 0, stream,
                     query, key, mask, b0, a0, b1, a1, Wout, bout, ws, attn);
  hipLaunchKernelGGL(din_pv, dim3(BB), dim3(256), 0, stream, val, attn, out);
}

// Round 9
// 228.852 us; speedup vs baseline: 1.2303x; 1.2303x over previous
//
#include <hip/hip_runtime.h>
#include <cstdint>

#define BB 2048
#define TT 200
#define DD 128
#define H1 128
#define H2 64
#define MASK_PAD -4294967295.0f

typedef __attribute__((ext_vector_type(8))) short short8;
typedef __attribute__((ext_vector_type(4))) float floatx4;

#define ATTN_OFF 57344  // float offset of attn[2048][200] in ws

static __device__ __forceinline__ unsigned short f2bf(float x) {
  union { float f; unsigned int u; } v; v.f = x;
  unsigned int r = v.u + 0x7FFF + ((v.u >> 16) & 1);  // RNE
  return (unsigned short)(r >> 16);
}

// ---------------------------------------------------------------------------
// Fold kernel -> ws:
//   Wqac[d][h] = W0a[d][h] + W0c[d][h]          fp32 [128][128] @ float 0
//   WkT [h][d] = (W0b - W0c)[d][h]              fp32 [128][128] @ float 16384
//   WdT [h][d] = W0d[d][h]                      fp32 [128][128] @ float 32768
//   W1tb[g][h] = bf16(W1[h][g])                 bf16 [64][128]  @ float 49152
// ---------------------------------------------------------------------------
__global__ void din_fold(const float* __restrict__ W0,
                         const float* __restrict__ W1,
                         float* __restrict__ ws) {
  int i = blockIdx.x * blockDim.x + threadIdx.x;
  if (i < 16384) {
    int d = i >> 7, h = i & 127;
    ws[i] = W0[d * 128 + h] + W0[(256 + d) * 128 + h];
  } else if (i < 32768) {
    int j = i - 16384; int h = j >> 7, d = j & 127;
    ws[16384 + j] = W0[(128 + d) * 128 + h] - W0[(256 + d) * 128 + h];
  } else if (i < 49152) {
    int j = i - 32768; int h = j >> 7, d = j & 127;
    ws[32768 + j] = W0[(384 + d) * 128 + h];
  } else if (i < 57344) {
    int j = i - 49152; int g = j >> 7, h = j & 127;
    ((unsigned short*)(ws + 49152))[j] = f2bf(W1[h * 64 + g]);
  }
}

// ---------------------------------------------------------------------------
// Kernel A: logits + softmax -> attn. One block per b, 4 waves.
// N-split register design (no spill, tiny LDS):
//   GEMM1: wave w owns h-cols [32w, 32w+32); B1f = WkT + q_d*WdT in 32 regs.
//   H0 exchanged through shared dbuf A2t (8 KB LDS), 1 barrier/tile.
//   GEMM2: wave w owns g-cols [16w, 16w+16); B2f in 16 regs.
//   Key rows + a0/a1 prefetched before GEMM1 (R6 lesson).
// ---------------------------------------------------------------------------
__global__ __launch_bounds__(256, 2) void din_logits(
    const float* __restrict__ query, const float* __restrict__ key,
    const int* __restrict__ mask,
    const float* __restrict__ b0, const float* __restrict__ a0,
    const float* __restrict__ b1, const float* __restrict__ a1,
    const float* __restrict__ Wout, const float* __restrict__ bout,
    const float* __restrict__ ws, float* __restrict__ attn_out) {
  const int b = blockIdx.x;
  const int tid = threadIdx.x;
  const int w = tid >> 6;
  const int l = tid & 63;

  __shared__ unsigned short A2t[2][16 * 128];  // 8 KB dbuf H0 (swizzled)
  __shared__ float qs[DD];
  __shared__ float qas[H1];
  __shared__ float logitsAll[208];
  __shared__ float partial[2][4][16];
  __shared__ float red4[8];

  const float* Wqac = ws;
  const float* WkT  = ws + 16384;
  const float* WdT  = ws + 32768;
  const unsigned short* W1tb = (const unsigned short*)(ws + 49152);

  // ---- stage q ----
  if (tid < DD) qs[tid] = query[(size_t)b * DD + tid];
  __syncthreads();

  const int kgrp = l >> 4;      // 0..3
  const int lr = l & 15;

  // ---- B1f: wave w owns n-tiles {2w,2w+1}; B_b[d][h]=WkT[h][d]+q_d*WdT[h][d]
  short8 B1f[2][4];
  #pragma unroll
  for (int ntl = 0; ntl < 2; ++ntl) {
    int h = (2 * w + ntl) * 16 + lr;
    #pragma unroll
    for (int ks = 0; ks < 4; ++ks) {
      int d0 = ks * 32 + kgrp * 8;
      const float* wk = WkT + h * 128 + d0;
      const float* wd = WdT + h * 128 + d0;
      short8 frag;
      #pragma unroll
      for (int e = 0; e < 8; ++e) {
        float v = wk[e] + qs[d0 + e] * wd[e];
        frag[e] = (short)f2bf(v);
      }
      B1f[ntl][ks] = frag;
    }
  }
  // ---- B2f: wave w owns g-cols 16w..16w+15 ----
  short8 B2f[4];
  {
    int g = w * 16 + lr;
    #pragma unroll
    for (int ks = 0; ks < 4; ++ks) {
      B2f[ks] = *(const short8*)(W1tb + g * 128 + ks * 32 + kgrp * 8);
    }
  }
  const float b1v = b1[w * 16 + lr];
  const float wov = Wout[w * 16 + lr];
  const float bout0 = bout[0];

  // ---- qA ----
  {
    int h = tid & 127, half = tid >> 7;
    float acc = half ? 0.0f : b0[h];
    const float* wq = Wqac + half * 64 * 128 + h;
    #pragma unroll 8
    for (int d = 0; d < 64; ++d) acc += qs[half * 64 + d] * wq[d * 128];
    if (half == 0) qas[h] = acc; else red4[0] = red4[0];  // placeholder
    // combine halves via LDS scratch
    __syncthreads();
    if (half == 1) atomicAdd(&qas[h], acc);
  }
  __syncthreads();  // qas ready

  // ---- prologue: prefetch first tile's key rows ----
  float4 fa[8];
  {
    int trow = lr; // mt=0
    const float* ar = key + ((size_t)b * TT + trow) * DD + kgrp * 8;
    #pragma unroll
    for (int ks = 0; ks < 4; ++ks) {
      fa[2 * ks]     = *(const float4*)(ar + ks * 32);
      fa[2 * ks + 1] = *(const float4*)(ar + ks * 32 + 4);
    }
  }

  int cur = 0;
  // =================== M-tile loop (1 barrier per tile) ===================
  #pragma unroll 1
  for (int mt = 0; mt < 13; ++mt) {
    // ---- cvt prefetched key -> af ----
    short8 af[4];
    #pragma unroll
    for (int ks = 0; ks < 4; ++ks) {
      float4 f0 = fa[2 * ks], f1 = fa[2 * ks + 1];
      short8 t;
      t[0] = (short)f2bf(f0.x); t[1] = (short)f2bf(f0.y);
      t[2] = (short)f2bf(f0.z); t[3] = (short)f2bf(f0.w);
      t[4] = (short)f2bf(f1.x); t[5] = (short)f2bf(f1.y);
      t[6] = (short)f2bf(f1.z); t[7] = (short)f2bf(f1.w);
      af[ks] = t;
    }
    // ---- prefetch NEXT tile's key (unconditional, clamped) ----
    {
      int trow = (mt + 1) * 16 + lr; if (trow > 199) trow = 199;
      const float* ar = key + ((size_t)b * TT + trow) * DD + kgrp * 8;
      #pragma unroll
      for (int ks = 0; ks < 4; ++ks) {
        fa[2 * ks]     = *(const float4*)(ar + ks * 32);
        fa[2 * ks + 1] = *(const float4*)(ar + ks * 32 + 4);
      }
    }
    // ---- prefetch this tile's a0 (wave's 32-col slice) and a1 (16-col) ----
    float a0v[2][4], a1v[4];
    #pragma unroll
    for (int r = 0; r < 4; ++r) {
      int tg = mt * 16 + kgrp * 4 + r; if (tg > 199) tg = 199;
      #pragma unroll
      for (int ntl = 0; ntl < 2; ++ntl)
        a0v[ntl][r] = a0[tg * H1 + (2 * w + ntl) * 16 + lr];
      a1v[r] = a1[tg * H2 + w * 16 + lr];
    }

    // ---- GEMM1: 2 n-tiles ----
    floatx4 acc1[2];
    acc1[0] = (floatx4)(0.0f); acc1[1] = (floatx4)(0.0f);
    #pragma unroll
    for (int ks = 0; ks < 4; ++ks) {
      acc1[0] = __builtin_amdgcn_mfma_f32_16x16x32_bf16(af[ks], B1f[0][ks], acc1[0], 0, 0, 0);
      acc1[1] = __builtin_amdgcn_mfma_f32_16x16x32_bf16(af[ks], B1f[1][ks], acc1[1], 0, 0, 0);
    }
    // ---- epilogue 1: +qA, PReLU(a0), write H0 slice to A2t[cur] (swz) ----
    #pragma unroll
    for (int ntl = 0; ntl < 2; ++ntl) {
      int h = (2 * w + ntl) * 16 + lr;
      float qa = qas[h];
      #pragma unroll
      for (int r = 0; r < 4; ++r) {
        int t_loc = kgrp * 4 + r;
        float v = acc1[ntl][r] + qa;
        float a = a0v[ntl][r];
        v = v > 0.0f ? v : a * v;
        *(unsigned short*)((char*)A2t[cur] + t_loc * 256 +
                           ((h * 2) ^ ((t_loc & 7) << 4))) = f2bf(v);
      }
    }
    __syncthreads();  // S1: A2t[cur] complete; partial[cur^1] visible

    // ---- combine previous tile's partials -> logits ----
    if (mt > 0 && tid < 16) {
      int tg = (mt - 1) * 16 + tid;
      if (tg < TT) {
        float lg = bout0 + partial[cur ^ 1][0][tid] + partial[cur ^ 1][1][tid] +
                   partial[cur ^ 1][2][tid] + partial[cur ^ 1][3][tid];
        int mk = mask[(size_t)b * TT + tg];
        logitsAll[tg] = (mk == 0) ? MASK_PAD : lg;
      }
    }

    // ---- GEMM2: full-width A from A2t[cur], B2f regs ----
    floatx4 acc2 = (floatx4)(0.0f);
    #pragma unroll
    for (int ks = 0; ks < 4; ++ks) {
      short8 a2f = *(const short8*)((const char*)A2t[cur] + lr * 256 +
                                    ((ks * 64 + kgrp * 16) ^ ((lr & 7) << 4)));
      acc2 = __builtin_amdgcn_mfma_f32_16x16x32_bf16(a2f, B2f[ks], acc2, 0, 0, 0);
    }
    // ---- epilogue 2: +b1, PReLU(a1), *Wout, 16-lane reduce -> partial ----
    {
      float p[4];
      #pragma unroll
      for (int r = 0; r < 4; ++r) {
        float x = acc2[r] + b1v;
        float a = a1v[r];
        x = x > 0.0f ? x : a * x;
        p[r] = x * wov;
      }
      #pragma unroll
      for (int m = 1; m < 16; m <<= 1) {
        #pragma unroll
        for (int r = 0; r < 4; ++r) p[r] += __shfl_xor(p[r], m);
      }
      if (lr == 0) {
        #pragma unroll
        for (int r = 0; r < 4; ++r) partial[cur][w][kgrp * 4 + r] = p[r];
      }
    }
    cur ^= 1;
  }
  __syncthreads();
  // combine last tile (mt=12 wrote partial[cur^1])
  if (tid < 16) {
    int tg = 192 + tid;
    if (tg < TT) {
      float lg = bout0 + partial[cur ^ 1][0][tid] + partial[cur ^ 1][1][tid] +
                 partial[cur ^ 1][2][tid] + partial[cur ^ 1][3][tid];
      int mk = mask[(size_t)b * TT + tg];
      logitsAll[tg] = (mk == 0) ? MASK_PAD : lg;
    }
  }
  __syncthreads();

  // =================== softmax -> normalized attn ===================
  float lv = (tid < TT) ? logitsAll[tid] : -INFINITY;
  {
    float m = lv;
    #pragma unroll
    for (int off = 32; off >= 1; off >>= 1) m = fmaxf(m, __shfl_xor(m, off));
    if (l == 0) red4[w] = m;
  }
  __syncthreads();
  float mx = fmaxf(fmaxf(red4[0], red4[1]), fmaxf(red4[2], red4[3]));
  float e = (tid < TT) ? __expf(lv - mx) : 0.0f;
  {
    float s = e;
    #pragma unroll
    for (int off = 32; off >= 1; off >>= 1) s += __shfl_xor(s, off);
    if (l == 0) red4[4 + w] = s;
  }
  __syncthreads();
  float denom = red4[4] + red4[5] + red4[6] + red4[7];
  float inv = 1.0f / denom;
  if (tid < TT) attn_out[(size_t)b * TT + tid] = e * inv;
}

// ---------------------------------------------------------------------------
// Kernel B: PV. out[b][d] = sum_t attn[b][t] * val[b][t][d].
// ---------------------------------------------------------------------------
__global__ __launch_bounds__(256) void din_pv(
    const float* __restrict__ val, const float* __restrict__ attn,
    float* __restrict__ out) {
  const int b = blockIdx.x;
  const int tid = threadIdx.x;
  __shared__ float eL[TT];
  __shared__ float red[8 * DD];

  if (tid < TT) eL[tid] = attn[(size_t)b * TT + tid];
  __syncthreads();

  const int group = tid >> 5;
  const int d4 = (tid & 31) * 4;
  const float* vb = val + (size_t)b * TT * DD;
  float4 acc4 = make_float4(0.f, 0.f, 0.f, 0.f);
  #pragma unroll 5
  for (int t = group * 25; t < group * 25 + 25; ++t) {
    float4 v = *(const float4*)(vb + (size_t)t * DD + d4);
    float wt = eL[t];
    acc4.x += wt * v.x; acc4.y += wt * v.y;
    acc4.z += wt * v.z; acc4.w += wt * v.w;
  }
  *(float4*)&red[group * DD + d4] = acc4;
  __syncthreads();
  if (tid < DD) {
    float s = 0.0f;
    #pragma unroll
    for (int g = 0; g < 8; ++g) s += red[g * DD + tid];
    out[(size_t)b * DD + tid] = s;
  }
}

extern "C" void kernel_launch(void* const* d_in, const int* in_sizes, int n_in,
                              void* d_out, int out_size, void* d_ws, size_t ws_size,
                              hipStream_t stream) {
  const float* query = (const float*)d_in[0];
  const float* key   = (const float*)d_in[1];
  const float* val   = (const float*)d_in[2];
  const int*   mask  = (const int*)d_in[3];
  const float* W0    = (const float*)d_in[4];
  const float* b0    = (const float*)d_in[5];
  const float* a0    = (const float*)d_in[6];
  const float* W1    = (const float*)d_in[7];
  const float* b1    = (const float*)d_in[8];
  const float* a1    = (const float*)d_in[9];
  const float* Wout  = (const float*)d_in[10];
  const float* bout  = (const float*)d_in[11];
  float* out = (float*)d_out;
  float* ws  = (float*)d_ws;
  float* attn = ws + ATTN_OFF;

  hipLaunchKernelGGL(din_fold, dim3(224), dim3(256), 0, stream, W0, W1, ws);
  hipLaunchKernelGGL(din_logits, dim3(BB), dim3(256), 0, stream,
                     query, key, mask, b0, a0, b1, a1, Wout, bout, ws, attn);
  hipLaunchKernelGGL(din_pv, dim3(BB), dim3(256), 0, stream, val, attn, out);
}